// Round 4
// baseline (238.863 us; speedup 1.0000x reference)
//
#include <hip/hip_runtime.h>
#include <hip/hip_fp16.h>
#include <math.h>

#define NITERS 50

typedef _Float16 h2_t __attribute__((ext_vector_type(2)));

#if defined(__has_builtin)
#if __has_builtin(__builtin_amdgcn_fdot2)
#define HAVE_FDOT2 1
#endif
#endif

__device__ __forceinline__ float fdot2f(unsigned int ka, unsigned int kb, float acc) {
#ifdef HAVE_FDOT2
    return __builtin_amdgcn_fdot2(__builtin_bit_cast(h2_t, ka),
                                  __builtin_bit_cast(h2_t, kb), acc, false);
#else
    h2_t a = __builtin_bit_cast(h2_t, ka);
    h2_t b = __builtin_bit_cast(h2_t, kb);
    return acc + (float)a.x * (float)b.x + (float)a.y * (float)b.y;
#endif
}

// One workgroup per batch. K0 (256x256 fp16, XOR-swizzled rows) lives in LDS.
// u=v=0 for all iterations (rescale provably never fires early; absorption is
// an exact identity), so iterate only (a,b) and finish with K = K0*a_i*b_j.
__global__ __launch_bounds__(512) void wfr_kernel(const float* __restrict__ D,
                                                  float* __restrict__ out) {
    __shared__ __align__(16) __half Ksh[256 * 256];   // 128 KiB
    __shared__ __align__(16) float  sh_bf[256];
    __shared__ __align__(16) float  sh_af[256];
    __shared__ __align__(16) float  sh_s2[256];
    __shared__ __align__(16) __half sh_bh[256];
    __shared__ __align__(16) float  part[512];
    __shared__ __align__(16) float  cpart[4096];      // 16 x 256 col partials

    const int tid = threadIdx.x;
    const int bb  = blockIdx.x;
    char* Kbytes  = reinterpret_cast<char*>(Ksh);

    // ---- build K0 = exp(-C/eps) = c^20,  c = cos(min(2D, pi/2)) + 1e-5 ----
    {
        const float4* D4 = reinterpret_cast<const float4*>(D + (size_t)bb * 65536);
        for (int k = 0; k < 32; ++k) {
            int idx4 = tid + (k << 9);            // 64 float4 per row -> wave == one row
            float4 d = D4[idx4];
            int i = idx4 >> 6;
            int j = (idx4 & 63) << 2;
            float v0[4] = {d.x, d.y, d.z, d.w};
            float k0[4];
            #pragma unroll
            for (int q = 0; q < 4; ++q) {
                float c = cosf(fminf(v0[q] * 2.0f, 1.57079632679489662f)) + 1e-5f;
                k0[q] = expf(20.0f * logf(c));    // == exp(-C/eps)
            }
            h2_t h01 = { (_Float16)k0[0], (_Float16)k0[1] };
            h2_t h23 = { (_Float16)k0[2], (_Float16)k0[3] };
            uint2 wv;
            wv.x = __builtin_bit_cast(unsigned int, h01);
            wv.y = __builtin_bit_cast(unsigned int, h23);
            int off = (i << 9) + (((j << 1) ^ ((i & 31) << 4)));
            *reinterpret_cast<uint2*>(Kbytes + off) = wv;
        }
    }
    if (tid < 256) {
        sh_bf[tid] = 1.0f;
        sh_bh[tid] = __float2half(1.0f);
    }
    __syncthreads();

    const int r   = tid & 255;   // row-pass: row, split in two column halves
    const int hh  = tid >> 8;
    const int rsw = r & 31;
    const char* Krow = Kbytes + (r << 9);
    const int g   = tid & 31;    // col-pass: 8-column group (16B chunk index)
    const int hc  = tid >> 5;    // col-pass: 16-row chunk (0..15)

    for (int it = 0; it < NITERS; ++it) {
        // ---------- row pass: s_i = mean_j K0[i][j] * b[j] ----------
        float s = 0.0f;
        #pragma unroll
        for (int c = 0; c < 16; ++c) {
            int chunk = (hh << 4) + c;
            uint4 kv = *reinterpret_cast<const uint4*>(Krow + ((chunk ^ rsw) << 4));
            uint4 bv = *reinterpret_cast<const uint4*>(
                reinterpret_cast<const char*>(sh_bh) + (chunk << 4));
            s = fdot2f(kv.x, bv.x, s);
            s = fdot2f(kv.y, bv.y, s);
            s = fdot2f(kv.z, bv.z, s);
            s = fdot2f(kv.w, bv.w, s);
        }
        part[tid] = s;
        __syncthreads();
        if (tid < 256) {
            float sf = (part[tid] + part[tid + 256]) * (1.0f / 256.0f);
            float a  = __powf(1.0f / sf, 1.0f / 1.1f);
            a = fminf(a, 1e30f);
            sh_af[tid] = a;
        }
        __syncthreads();

        // ---------- col pass: s2_j = mean_i K0[i][j] * a[i] ----------
        float f0=0,f1=0,f2=0,f3=0,f4=0,f5=0,f6=0,f7=0;
        #pragma unroll
        for (int m = 0; m < 16; ++m) {
            int i = (hc << 4) + m;
            float ai = sh_af[i];
            uint4 kv = *reinterpret_cast<const uint4*>(
                Kbytes + (i << 9) + ((g ^ (i & 31)) << 4));
            h2_t p0 = __builtin_bit_cast(h2_t, kv.x);
            h2_t p1 = __builtin_bit_cast(h2_t, kv.y);
            h2_t p2 = __builtin_bit_cast(h2_t, kv.z);
            h2_t p3 = __builtin_bit_cast(h2_t, kv.w);
            f0 = fmaf((float)p0.x, ai, f0);
            f1 = fmaf((float)p0.y, ai, f1);
            f2 = fmaf((float)p1.x, ai, f2);
            f3 = fmaf((float)p1.y, ai, f3);
            f4 = fmaf((float)p2.x, ai, f4);
            f5 = fmaf((float)p2.y, ai, f5);
            f6 = fmaf((float)p3.x, ai, f6);
            f7 = fmaf((float)p3.y, ai, f7);
        }
        {
            float* cp = cpart + (hc << 8) + (g << 3);
            *reinterpret_cast<float4*>(cp)     = make_float4(f0, f1, f2, f3);
            *reinterpret_cast<float4*>(cp + 4) = make_float4(f4, f5, f6, f7);
        }
        __syncthreads();
        if (tid < 256) {
            float s2 = 0.0f;
            #pragma unroll
            for (int q = 0; q < 16; ++q) s2 += cpart[(q << 8) + tid];
            s2 *= (1.0f / 256.0f);
            float bn = __powf(1.0f / s2, 1.0f / 1.1f);
            bn = fminf(bn, 1e30f);
            sh_bf[tid] = bn;
            sh_bh[tid] = __float2half(bn);
            sh_s2[tid] = s2;
        }
        __syncthreads();
    }

    // ---- final: row sums with final b, plus transport partials ----
    // K_final = K0 * a_i * b_j ;  C recovered as -0.1*ln(K0)
    {
        float s = 0.0f, tp = 0.0f;
        #pragma unroll
        for (int c = 0; c < 16; ++c) {
            int chunk = (hh << 4) + c;
            uint4 kv = *reinterpret_cast<const uint4*>(Krow + ((chunk ^ rsw) << 4));
            float4 blo = *reinterpret_cast<const float4*>(sh_bf + (chunk << 3));
            float4 bhi = *reinterpret_cast<const float4*>(sh_bf + (chunk << 3) + 4);
            h2_t p0 = __builtin_bit_cast(h2_t, kv.x);
            h2_t p1 = __builtin_bit_cast(h2_t, kv.y);
            h2_t p2 = __builtin_bit_cast(h2_t, kv.z);
            h2_t p3 = __builtin_bit_cast(h2_t, kv.w);
            float kf[8] = {(float)p0.x,(float)p0.y,(float)p1.x,(float)p1.y,
                           (float)p2.x,(float)p2.y,(float)p3.x,(float)p3.y};
            float bf[8] = {blo.x,blo.y,blo.z,blo.w,bhi.x,bhi.y,bhi.z,bhi.w};
            #pragma unroll
            for (int q = 0; q < 8; ++q) {
                float prod = kf[q] * bf[q];
                s += prod;
                float cl = (kf[q] > 0.0f) ? (-0.1f * __logf(kf[q])) : 0.0f;
                tp = fmaf(prod, cl, tp);
            }
        }
        part[tid]  = s;
        cpart[tid] = tp;
    }
    __syncthreads();
    float val = 0.0f;
    if (tid < 256) {
        float sfin     = (part[tid] + part[tid + 256]) * (1.0f / 256.0f);
        float af       = sh_af[tid];
        float row_marg = af * sfin;                    // a_i * mean_j K0*b
        float col_marg = sh_bf[tid] * sh_s2[tid];      // b_j * mean_i K0*a
        float tprow    = af * (cpart[tid] + cpart[tid + 256]);
        float d1  = row_marg / (1.0f + 1e-10f);
        float kl1 = d1 * __logf(d1 + 1e-10f) - d1 + 1.0f;
        float d2  = col_marg / (1.0f + 1e-10f);
        float kl2 = d2 * __logf(d2 + 1e-10f) - d2 + 1.0f;
        val = (kl1 + kl2) * (1.0f / 256.0f) + tprow * (1.0f / 65536.0f);
    }
    __syncthreads();
    part[tid] = val;
    __syncthreads();
    for (int off = 256; off > 0; off >>= 1) {
        if (tid < off) part[tid] += part[tid + off];
        __syncthreads();
    }
    if (tid == 0) out[bb] = part[0];
}

extern "C" void kernel_launch(void* const* d_in, const int* in_sizes, int n_in,
                              void* d_out, int out_size, void* d_ws, size_t ws_size,
                              hipStream_t stream) {
    (void)in_sizes; (void)n_in; (void)d_ws; (void)ws_size; (void)out_size;
    const float* D = reinterpret_cast<const float*>(d_in[0]);
    float* out     = reinterpret_cast<float*>(d_out);
    wfr_kernel<<<dim3(256), dim3(512), 0, stream>>>(D, out);
}

// Round 6
// 204.549 us; speedup vs baseline: 1.1678x; 1.1678x over previous
//
#include <hip/hip_runtime.h>
#include <hip/hip_fp16.h>
#include <math.h>

#define NITERS 50

typedef _Float16 h2_t __attribute__((ext_vector_type(2)));

#if defined(__has_builtin)
#if __has_builtin(__builtin_amdgcn_fdot2)
#define HAVE_FDOT2 1
#endif
#endif

__device__ __forceinline__ float fdot2f(unsigned int ka, unsigned int kb, float acc) {
#ifdef HAVE_FDOT2
    return __builtin_amdgcn_fdot2(__builtin_bit_cast(h2_t, ka),
                                  __builtin_bit_cast(h2_t, kb), acc, false);
#else
    h2_t a = __builtin_bit_cast(h2_t, ka);
    h2_t b = __builtin_bit_cast(h2_t, kb);
    return acc + (float)a.x * (float)b.x + (float)a.y * (float)b.y;
#endif
}

// One workgroup per batch. K0 built once in LDS (XOR-swizzled rows), then each
// thread pulls its row-pass slice (row r, 128 cols) AND col-pass slice (16 rows
// x 8 cols) into REGISTERS (64+64 VGPRs packed fp16). All 50 iterations run
// out of registers; LDS carries only the b/a vectors and reduction buffers.
// u=v=0 throughout (rescale provably never fires early; absorption exact).
__global__ __launch_bounds__(512, 2) void wfr_kernel(const float* __restrict__ D,
                                                     float* __restrict__ out) {
    __shared__ __align__(16) __half Ksh[256 * 256];   // 128 KiB (build+stage only)
    __shared__ __align__(16) float  sh_bf[256];
    __shared__ __align__(16) float  sh_af[256];
    __shared__ __align__(16) float  sh_s2[256];
    __shared__ __align__(16) __half sh_bh[256];
    __shared__ __align__(16) float  part[512];
    __shared__ __align__(16) float  cpart[4096];      // 16 x 256 col partials

    const int tid = threadIdx.x;
    const int bb  = blockIdx.x;
    char* Kbytes  = reinterpret_cast<char*>(Ksh);

    // ---- build K0 = exp(-C/eps) = c^20,  c = cos(min(2D, pi/2)) + 1e-5 ----
    {
        const float4* D4 = reinterpret_cast<const float4*>(D + (size_t)bb * 65536);
        for (int k = 0; k < 32; ++k) {
            int idx4 = tid + (k << 9);            // 64 float4 per row -> wave == one row
            float4 d = D4[idx4];
            int i = idx4 >> 6;
            int j = (idx4 & 63) << 2;
            float v0[4] = {d.x, d.y, d.z, d.w};
            float k0[4];
            #pragma unroll
            for (int q = 0; q < 4; ++q) {
                float c = cosf(fminf(v0[q] * 2.0f, 1.57079632679489662f)) + 1e-5f;
                k0[q] = expf(20.0f * logf(c));    // == exp(-C/eps)
            }
            h2_t h01 = { (_Float16)k0[0], (_Float16)k0[1] };
            h2_t h23 = { (_Float16)k0[2], (_Float16)k0[3] };
            uint2 wv;
            wv.x = __builtin_bit_cast(unsigned int, h01);
            wv.y = __builtin_bit_cast(unsigned int, h23);
            int off = (i << 9) + (((j << 1) ^ ((i & 31) << 4)));
            *reinterpret_cast<uint2*>(Kbytes + off) = wv;
        }
    }
    if (tid < 256) {
        sh_bf[tid] = 1.0f;
        sh_bh[tid] = __float2half(1.0f);
    }
    __syncthreads();

    const int r   = tid & 255;   // row-pass: row, split in two column halves
    const int hh  = tid >> 8;
    const int rsw = r & 31;
    const char* Krow = Kbytes + (r << 9);
    const int g   = tid & 31;    // col-pass: 8-column group (16B chunk index)
    const int hc  = tid >> 5;    // col-pass: 16-row chunk (0..15)

    // ---- stage K slices into registers (once) ----
    uint4 krow4[16];             // row r, cols [hh*128 .. hh*128+127]
    #pragma unroll
    for (int c = 0; c < 16; ++c) {
        int chunk = (hh << 4) + c;
        krow4[c] = *reinterpret_cast<const uint4*>(Krow + ((chunk ^ rsw) << 4));
    }
    uint4 kcol4[16];             // rows [hc*16 .. +15], cols [g*8 .. +7]
    #pragma unroll
    for (int m = 0; m < 16; ++m) {
        int i = (hc << 4) + m;
        kcol4[m] = *reinterpret_cast<const uint4*>(
            Kbytes + (i << 9) + ((g ^ (i & 31)) << 4));
    }

    for (int it = 0; it < NITERS; ++it) {
        // ---------- row pass: s_i = mean_j K0[i][j] * b[j] (registers) ----------
        float s0 = 0.0f, s1 = 0.0f, s2a = 0.0f, s3 = 0.0f;
        #pragma unroll
        for (int c = 0; c < 16; ++c) {
            uint4 bv = *reinterpret_cast<const uint4*>(
                reinterpret_cast<const char*>(sh_bh) + (((hh << 4) + c) << 4));
            s0  = fdot2f(krow4[c].x, bv.x, s0);
            s1  = fdot2f(krow4[c].y, bv.y, s1);
            s2a = fdot2f(krow4[c].z, bv.z, s2a);
            s3  = fdot2f(krow4[c].w, bv.w, s3);
        }
        part[tid] = (s0 + s1) + (s2a + s3);
        __syncthreads();
        if (tid < 256) {
            float sf = (part[tid] + part[tid + 256]) * (1.0f / 256.0f);
            float a  = __powf(1.0f / sf, 1.0f / 1.1f);
            a = fminf(a, 1e30f);
            sh_af[tid] = a;
        }
        __syncthreads();

        // ---------- col pass: s2_j = mean_i K0[i][j] * a[i] (registers) ----------
        float f0=0,f1=0,f2=0,f3=0,f4=0,f5=0,f6=0,f7=0;
        #pragma unroll
        for (int m = 0; m < 16; ++m) {
            float ai = sh_af[(hc << 4) + m];
            h2_t p0 = __builtin_bit_cast(h2_t, kcol4[m].x);
            h2_t p1 = __builtin_bit_cast(h2_t, kcol4[m].y);
            h2_t p2 = __builtin_bit_cast(h2_t, kcol4[m].z);
            h2_t p3 = __builtin_bit_cast(h2_t, kcol4[m].w);
            f0 = fmaf((float)p0.x, ai, f0);
            f1 = fmaf((float)p0.y, ai, f1);
            f2 = fmaf((float)p1.x, ai, f2);
            f3 = fmaf((float)p1.y, ai, f3);
            f4 = fmaf((float)p2.x, ai, f4);
            f5 = fmaf((float)p2.y, ai, f5);
            f6 = fmaf((float)p3.x, ai, f6);
            f7 = fmaf((float)p3.y, ai, f7);
        }
        {
            float* cp = cpart + (hc << 8) + (g << 3);
            *reinterpret_cast<float4*>(cp)     = make_float4(f0, f1, f2, f3);
            *reinterpret_cast<float4*>(cp + 4) = make_float4(f4, f5, f6, f7);
        }
        __syncthreads();
        if (tid < 256) {
            float s2 = 0.0f;
            #pragma unroll
            for (int q = 0; q < 16; ++q) s2 += cpart[(q << 8) + tid];
            s2 *= (1.0f / 256.0f);
            float bn = __powf(1.0f / s2, 1.0f / 1.1f);
            bn = fminf(bn, 1e30f);
            sh_bf[tid] = bn;
            sh_bh[tid] = __float2half(bn);
            sh_s2[tid] = s2;
        }
        __syncthreads();
    }

    // ---- final: row sums with final b, plus transport partials (registers) ----
    // K_final = K0 * a_i * b_j ;  C recovered as -0.1*ln(K0)
    {
        float s = 0.0f, tp = 0.0f;
        #pragma unroll
        for (int c = 0; c < 16; ++c) {
            int chunk = (hh << 4) + c;
            float4 blo = *reinterpret_cast<const float4*>(sh_bf + (chunk << 3));
            float4 bhi = *reinterpret_cast<const float4*>(sh_bf + (chunk << 3) + 4);
            h2_t p0 = __builtin_bit_cast(h2_t, krow4[c].x);
            h2_t p1 = __builtin_bit_cast(h2_t, krow4[c].y);
            h2_t p2 = __builtin_bit_cast(h2_t, krow4[c].z);
            h2_t p3 = __builtin_bit_cast(h2_t, krow4[c].w);
            float kf[8] = {(float)p0.x,(float)p0.y,(float)p1.x,(float)p1.y,
                           (float)p2.x,(float)p2.y,(float)p3.x,(float)p3.y};
            float bf[8] = {blo.x,blo.y,blo.z,blo.w,bhi.x,bhi.y,bhi.z,bhi.w};
            #pragma unroll
            for (int q = 0; q < 8; ++q) {
                float prod = kf[q] * bf[q];
                s += prod;
                float cl = (kf[q] > 0.0f) ? (-0.1f * __logf(kf[q])) : 0.0f;
                tp = fmaf(prod, cl, tp);
            }
        }
        part[tid]  = s;
        cpart[tid] = tp;
    }
    __syncthreads();
    float val = 0.0f;
    if (tid < 256) {
        float sfin     = (part[tid] + part[tid + 256]) * (1.0f / 256.0f);
        float af       = sh_af[tid];
        float row_marg = af * sfin;                    // a_i * mean_j K0*b
        float col_marg = sh_bf[tid] * sh_s2[tid];      // b_j * mean_i K0*a
        float tprow    = af * (cpart[tid] + cpart[tid + 256]);
        float d1  = row_marg / (1.0f + 1e-10f);
        float kl1 = d1 * __logf(d1 + 1e-10f) - d1 + 1.0f;
        float d2  = col_marg / (1.0f + 1e-10f);
        float kl2 = d2 * __logf(d2 + 1e-10f) - d2 + 1.0f;
        val = (kl1 + kl2) * (1.0f / 256.0f) + tprow * (1.0f / 65536.0f);
    }
    __syncthreads();
    part[tid] = val;
    __syncthreads();
    for (int off = 256; off > 0; off >>= 1) {
        if (tid < off) part[tid] += part[tid + off];
        __syncthreads();
    }
    if (tid == 0) out[bb] = part[0];
}

extern "C" void kernel_launch(void* const* d_in, const int* in_sizes, int n_in,
                              void* d_out, int out_size, void* d_ws, size_t ws_size,
                              hipStream_t stream) {
    (void)in_sizes; (void)n_in; (void)d_ws; (void)ws_size; (void)out_size;
    const float* D = reinterpret_cast<const float*>(d_in[0]);
    float* out     = reinterpret_cast<float*>(d_out);
    wfr_kernel<<<dim3(256), dim3(512), 0, stream>>>(D, out);
}